// Round 4
// baseline (383.397 us; speedup 1.0000x reference)
//
#include <hip/hip_runtime.h>
#include <math.h>

#define N_NODES 100000
#define N_EDGES 1600000
#define NF 16        // node features
#define HID 32
#define OUTD 12
#define CIN3 48      // x | T_o | T_i

#define NB   512                 // buckets per direction
#define RNG  196                 // nodes per bucket: 512*196 = 100352 >= 100000
#define PBLK 256                 // partition blocks
#define CHUNK ((N_EDGES + PBLK - 1) / PBLK)   // 6250

typedef unsigned int uint;

// ============================================================================
// MAIN PATH: radix-partition edges by dst (To) and src (Ti), then accumulate
// in LDS per bucket. No device-scope atomics anywhere on the heavy path.
// ============================================================================

// ---- P1: per-block bucket histograms (LDS counters) ----
__global__ __launch_bounds__(256)
void p1_count(const int* __restrict__ ei, uint* __restrict__ cntD, uint* __restrict__ cntS) {
    __shared__ uint cD[NB], cS[NB];
    int t = threadIdx.x, blk = blockIdx.x;
    for (int i = t; i < NB; i += 256) { cD[i] = 0; cS[i] = 0; }
    __syncthreads();
    int lo = blk * CHUNK, hi = min(lo + CHUNK, N_EDGES);
    for (int e = lo + t; e < hi; e += 256) {
        uint s = (uint)ei[e];
        uint d = (uint)ei[N_EDGES + e];
        atomicAdd(&cS[s / RNG], 1u);
        atomicAdd(&cD[d / RNG], 1u);
    }
    __syncthreads();
    for (int i = t; i < NB; i += 256) {
        cntD[i * PBLK + blk] = cD[i];
        cntS[i * PBLK + blk] = cS[i];
    }
}

// ---- P2a: bucket totals (row sums over blocks); grid 2*NB ----
__global__ __launch_bounds__(256)
void p2a_rowsum(const uint* __restrict__ cntD, const uint* __restrict__ cntS,
                uint* __restrict__ totD, uint* __restrict__ totS) {
    __shared__ uint red[256];
    int t = threadIdx.x;
    bool isS = blockIdx.x >= NB;
    int b = isS ? (blockIdx.x - NB) : blockIdx.x;
    const uint* cnt = isS ? cntS : cntD;
    red[t] = cnt[b * PBLK + t];
    __syncthreads();
    for (int s = 128; s > 0; s >>= 1) { if (t < s) red[t] += red[t + s]; __syncthreads(); }
    if (t == 0) (isS ? totS : totD)[b] = red[0];
}

// ---- P2b: exclusive scan of bucket totals -> baseD/baseS (NB+1 each) ----
__global__ __launch_bounds__(256)
void p2b_scan(const uint* __restrict__ totD, const uint* __restrict__ totS,
              uint* __restrict__ baseD, uint* __restrict__ baseS) {
    __shared__ uint sD[NB + 1], sS[NB + 1];
    int t = threadIdx.x;
    for (int i = t; i < NB; i += 256) { sD[i] = totD[i]; sS[i] = totS[i]; }
    __syncthreads();
    if (t == 0) {
        uint a = 0; for (int b = 0; b < NB; ++b) { uint v = sD[b]; sD[b] = a; a += v; } sD[NB] = a;
        a = 0;      for (int b = 0; b < NB; ++b) { uint v = sS[b]; sS[b] = a; a += v; } sS[NB] = a;
    }
    __syncthreads();
    for (int i = t; i < NB + 1; i += 256) { baseD[i] = sD[i]; baseS[i] = sS[i]; }
}

// ---- P2c: per-bucket exclusive scan across blocks + base -> off; grid 2*NB ----
__global__ __launch_bounds__(256)
void p2c_rowscan(const uint* __restrict__ cntD, const uint* __restrict__ cntS,
                 const uint* __restrict__ baseD, const uint* __restrict__ baseS,
                 uint* __restrict__ offD, uint* __restrict__ offS) {
    __shared__ uint row[PBLK];
    int t = threadIdx.x;
    bool isS = blockIdx.x >= NB;
    int b = isS ? (blockIdx.x - NB) : blockIdx.x;
    const uint* cnt = isS ? cntS : cntD;
    const uint* base = isS ? baseS : baseD;
    uint* off = isS ? offS : offD;
    row[t] = cnt[b * PBLK + t];
    __syncthreads();
    if (t == 0) {
        uint a = base[b];
        for (int k = 0; k < PBLK; ++k) { uint v = row[k]; row[k] = a; a += v; }
    }
    __syncthreads();
    off[b * PBLK + t] = row[t];
}

// ---- P3: reorder edges into bucket-contiguous records (plain stores) ----
// record.x = other_node | (local_node << 20); record.y = bits(edge_weight)
__global__ __launch_bounds__(256)
void p3_scatter(const int* __restrict__ ei, const float* __restrict__ ew,
                const uint* __restrict__ offD, const uint* __restrict__ offS,
                uint2* __restrict__ recD, uint2* __restrict__ recS) {
    __shared__ uint curD[NB], curS[NB];
    int t = threadIdx.x, blk = blockIdx.x;
    for (int b = t; b < NB; b += 256) {
        curD[b] = offD[b * PBLK + blk];
        curS[b] = offS[b * PBLK + blk];
    }
    __syncthreads();
    int lo = blk * CHUNK, hi = min(lo + CHUNK, N_EDGES);
    for (int e = lo + t; e < hi; e += 256) {
        uint s = (uint)ei[e];
        uint d = (uint)ei[N_EDGES + e];
        uint w = __float_as_uint(ew[e]);
        uint bd = d / RNG, dl = d - bd * RNG;
        uint p = atomicAdd(&curD[bd], 1u);          // LDS atomic (block-local)
        recD[p] = make_uint2(s | (dl << 20), w);
        uint bs = s / RNG, sl = s - bs * RNG;
        uint p2 = atomicAdd(&curS[bs], 1u);
        recS[p2] = make_uint2(d | (sl << 20), w);
    }
}

// ---- KDEG: per-bucket weighted degree in LDS -> inverse; grid 2*NB ----
// D-binned records give deg_in (sum w per dst); S-binned give deg_out.
__global__ __launch_bounds__(256)
void kdeg(const uint2* __restrict__ recD, const uint2* __restrict__ recS,
          const uint* __restrict__ baseD, const uint* __restrict__ baseS,
          float* __restrict__ inv_in, float* __restrict__ inv_out) {
    __shared__ float dacc[RNG];
    int t = threadIdx.x;
    bool isS = blockIdx.x >= NB;
    int b = isS ? (blockIdx.x - NB) : blockIdx.x;
    const uint2* rec = isS ? recS : recD;
    const uint* base = isS ? baseS : baseD;
    float* inv = isS ? inv_out : inv_in;
    for (int i = t; i < RNG; i += 256) dacc[i] = 0.0f;
    __syncthreads();
    uint lo = base[b], hi = base[b + 1];
    for (uint e = lo + t; e < hi; e += 256) {
        uint2 r = rec[e];
        atomicAdd(&dacc[r.x >> 20], __uint_as_float(r.y));   // LDS atomic
    }
    __syncthreads();
    int n0 = b * RNG;
    for (int i = t; i < RNG; i += 256) {
        int n = n0 + i;
        if (n < N_NODES) inv[n] = 1.0f / dacc[i];   // inf for isolated nodes: never consumed
    }
}

// ---- P4: per-bucket gather-accumulate in LDS, sequential write-out; grid 2*NB ----
// To[dst] = sum_src x[src]*inv_out[src]  (D-binned)
// Ti[src] = sum_dst x[dst]*inv_in[dst]   (S-binned)
__global__ __launch_bounds__(256)
void p4_gather(const uint2* __restrict__ recD, const uint2* __restrict__ recS,
               const uint* __restrict__ baseD, const uint* __restrict__ baseS,
               const float* __restrict__ x,
               const float* __restrict__ inv_out, const float* __restrict__ inv_in,
               float* __restrict__ To, float* __restrict__ Ti) {
    __shared__ float acc[RNG * NF];   // 12544 B
    int t = threadIdx.x;
    bool isS = blockIdx.x >= NB;
    int b = isS ? (blockIdx.x - NB) : blockIdx.x;
    const uint2* rec = isS ? recS : recD;
    const uint* base = isS ? baseS : baseD;
    const float* inv = isS ? inv_in : inv_out;
    float* out = isS ? Ti : To;
    for (int i = t; i < RNG * NF; i += 256) acc[i] = 0.0f;
    __syncthreads();
    uint lo = base[b], hi = base[b + 1];
    int f = t & 15, g = t >> 4;       // 16 lanes per edge, 16 groups per block
    for (uint e = lo + g; e < hi; e += 16) {
        uint r = rec[e].x;
        uint other = r & 0xFFFFFu;
        uint loc = r >> 20;
        float v = x[other * NF + f] * inv[other];   // coalesced 64B gather + broadcast scalar
        atomicAdd(&acc[loc * NF + f], v);           // LDS atomic
    }
    __syncthreads();
    size_t o0 = (size_t)b * RNG * NF;
    int lim = N_NODES * NF - (int)o0;
    for (int i = t; i < RNG * NF; i += 256)
        if (i < lim) out[o0 + i] = acc[i];          // fully sequential store
}

// ---- combine + TRANSPOSE weights: WT[h][c] ----
// c 0..15  : W[0,0,c,:] + W[1,0,c,:]   (K=0 term, both directions; only x-channels alive)
// c 16..31 : W[0,1,c-16,:]  (forward diffusion)   c 32..47 : W[1,1,c-32,:] (reverse)
__global__ void wprep_kernel(const float* __restrict__ Wz, const float* __restrict__ Wh,
                             float* __restrict__ WzT, float* __restrict__ WhT) {
    int t = blockIdx.x * blockDim.x + threadIdx.x;
    if (t >= 2 * CIN3 * HID) return;
    const float* W = (t < CIN3 * HID) ? Wz : Wh;
    float* WT      = (t < CIN3 * HID) ? WzT : WhT;
    int i = (t < CIN3 * HID) ? t : (t - CIN3 * HID);
    int c = i / HID;
    int h = i - c * HID;
    float v;
    if (c < 16)      v = W[(0 * 48 + c) * 32 + h] + W[(2 * 48 + c) * 32 + h];
    else if (c < 32) v = W[(1 * 48 + (c - 16)) * 32 + h];
    else             v = W[(3 * 48 + (c - 32)) * 32 + h];
    WT[h * CIN3 + c] = v;
}

// ---- per-node fused GRU-collapse + output ----
__global__ __launch_bounds__(256)
void node_kernel(const float* __restrict__ x, const float* __restrict__ To,
                 const float* __restrict__ Ti,
                 const float* __restrict__ WzT, const float* __restrict__ WhT,
                 const float* __restrict__ bz, const float* __restrict__ bh,
                 const float* __restrict__ linW, const float* __restrict__ linb,
                 float* __restrict__ out) {
    __shared__ __align__(16) float sWz[HID * CIN3];
    __shared__ __align__(16) float sWh[HID * CIN3];
    __shared__ __align__(16) float sBz[HID], sBh[HID];
    __shared__ __align__(16) float sLW[HID * OUTD];
    __shared__ __align__(16) float sLb[OUTD];

    for (int i = threadIdx.x; i < HID * CIN3; i += 256) { sWz[i] = WzT[i]; sWh[i] = WhT[i]; }
    if (threadIdx.x < HID) { sBz[threadIdx.x] = bz[threadIdx.x]; sBh[threadIdx.x] = bh[threadIdx.x]; }
    for (int i = threadIdx.x; i < HID * OUTD; i += 256) sLW[i] = linW[i];
    if (threadIdx.x < OUTD) sLb[threadIdx.x] = linb[threadIdx.x];
    __syncthreads();

    int n = blockIdx.x * 256 + threadIdx.x;
    if (n >= N_NODES) return;

    float feat[CIN3];
#pragma unroll
    for (int q = 0; q < 4; ++q) {
        float4 v = ((const float4*)(x + (size_t)n * NF))[q];
        feat[q*4+0]=v.x; feat[q*4+1]=v.y; feat[q*4+2]=v.z; feat[q*4+3]=v.w;
    }
#pragma unroll
    for (int q = 0; q < 4; ++q) {
        float4 v = ((const float4*)(To + (size_t)n * NF))[q];
        feat[16+q*4+0]=v.x; feat[16+q*4+1]=v.y; feat[16+q*4+2]=v.z; feat[16+q*4+3]=v.w;
    }
#pragma unroll
    for (int q = 0; q < 4; ++q) {
        float4 v = ((const float4*)(Ti + (size_t)n * NF))[q];
        feat[32+q*4+0]=v.x; feat[32+q*4+1]=v.y; feat[32+q*4+2]=v.z; feat[32+q*4+3]=v.w;
    }

    float o[OUTD];
#pragma unroll
    for (int j = 0; j < OUTD; ++j) o[j] = sLb[j];

#pragma unroll 2
    for (int h = 0; h < HID; ++h) {
        float az = sBz[h];
        float ah = sBh[h];
        const float4* wz4 = (const float4*)(sWz + h * CIN3);
        const float4* wh4 = (const float4*)(sWh + h * CIN3);
#pragma unroll
        for (int q = 0; q < CIN3 / 4; ++q) {
            float4 wz = wz4[q];
            float4 wh = wh4[q];
            float f0 = feat[q*4+0], f1 = feat[q*4+1], f2 = feat[q*4+2], f3 = feat[q*4+3];
            az += f0*wz.x + f1*wz.y + f2*wz.z + f3*wz.w;
            ah += f0*wh.x + f1*wh.y + f2*wh.z + f3*wh.w;
        }
        float z  = 1.0f / (1.0f + expf(-az));
        float ht = tanhf(ah);
        float r  = fmaxf((1.0f - z) * ht, 0.0f);
#pragma unroll
        for (int j = 0; j < OUTD; ++j) o[j] += r * sLW[h * OUTD + j];
    }

    float4* op = (float4*)(out + (size_t)n * OUTD);
    op[0] = make_float4(o[0], o[1], o[2],  o[3]);
    op[1] = make_float4(o[4], o[5], o[6],  o[7]);
    op[2] = make_float4(o[8], o[9], o[10], o[11]);
}

// ============================================================================
// FALLBACK (ws too small): round-2 atomic path
// ============================================================================
__global__ void zero_kernel(float* __restrict__ p, int n) {
    int i = blockIdx.x * blockDim.x + threadIdx.x;
    int stride = gridDim.x * blockDim.x;
    for (; i < n; i += stride) p[i] = 0.0f;
}
__global__ void degree_compact(const int* __restrict__ ei, const float* __restrict__ ew,
                               float* __restrict__ deg_out, float* __restrict__ deg_in) {
    int e = blockIdx.x * blockDim.x + threadIdx.x;
    if (e >= N_EDGES) return;
    atomicAdd(&deg_out[ei[e]], ew[e]);
    atomicAdd(&deg_in[ei[N_EDGES + e]], ew[e]);
}
__global__ void rcp_compact(float* __restrict__ a, float* __restrict__ b) {
    int n = blockIdx.x * blockDim.x + threadIdx.x;
    if (n >= N_NODES) return;
    a[n] = 1.0f / a[n]; b[n] = 1.0f / b[n];
}
__global__ __launch_bounds__(256)
void scatter_kernel(const int* __restrict__ ei, const float* __restrict__ x,
                    const float* __restrict__ inv_out, const float* __restrict__ inv_in,
                    float* __restrict__ To, float* __restrict__ Ti) {
    int t = blockIdx.x * blockDim.x + threadIdx.x;
    if (t >= N_EDGES * NF) return;
    int e = t >> 4, f = t & 15;
    int src = ei[e], dst = ei[N_EDGES + e];
    atomicAdd(&To[dst * NF + f], x[src * NF + f] * inv_out[src]);
    atomicAdd(&Ti[src * NF + f], x[dst * NF + f] * inv_in[dst]);
}

// ============================================================================
extern "C" void kernel_launch(void* const* d_in, const int* in_sizes, int n_in,
                              void* d_out, int out_size, void* d_ws, size_t ws_size,
                              hipStream_t stream) {
    const float* x    = (const float*)d_in[0];
    const int*   ei   = (const int*)  d_in[1];
    const float* ew   = (const float*)d_in[2];
    const float* Wz   = (const float*)d_in[3];
    const float* bz   = (const float*)d_in[4];
    // d_in[5], d_in[6] (W_r, b_r) dead: H0 == 0 makes the reset gate unused.
    const float* Wh   = (const float*)d_in[7];
    const float* bh   = (const float*)d_in[8];
    const float* linW = (const float*)d_in[9];
    const float* linb = (const float*)d_in[10];

    float* ws = (float*)d_ws;

    // ---- main-path workspace layout (dwords) ----
    size_t off = 0;
    uint2* recD = (uint2*)(ws + off); off += 2 * (size_t)N_EDGES;
    uint2* recS = (uint2*)(ws + off); off += 2 * (size_t)N_EDGES;
    uint* cntD  = (uint*)(ws + off);  off += NB * PBLK;
    uint* cntS  = (uint*)(ws + off);  off += NB * PBLK;
    uint* offD  = (uint*)(ws + off);  off += NB * PBLK;
    uint* offS  = (uint*)(ws + off);  off += NB * PBLK;
    uint* totD  = (uint*)(ws + off);  off += NB;
    uint* totS  = (uint*)(ws + off);  off += NB;
    uint* baseD = (uint*)(ws + off);  off += NB + 1;
    uint* baseS = (uint*)(ws + off);  off += NB + 1;
    float* inv_out = ws + off;        off += N_NODES;
    float* inv_in  = ws + off;        off += N_NODES;
    float* To      = ws + off;        off += (size_t)NF * N_NODES;
    float* Ti      = ws + off;        off += (size_t)NF * N_NODES;
    float* WzT     = ws + off;        off += CIN3 * HID;
    float* WhT     = ws + off;        off += CIN3 * HID;
    size_t need = off * sizeof(float);

    if (ws_size >= need) {
        p1_count   <<<PBLK,  256, 0, stream>>>(ei, cntD, cntS);
        p2a_rowsum <<<2*NB,  256, 0, stream>>>(cntD, cntS, totD, totS);
        p2b_scan   <<<1,     256, 0, stream>>>(totD, totS, baseD, baseS);
        p2c_rowscan<<<2*NB,  256, 0, stream>>>(cntD, cntS, baseD, baseS, offD, offS);
        p3_scatter <<<PBLK,  256, 0, stream>>>(ei, ew, offD, offS, recD, recS);
        kdeg       <<<2*NB,  256, 0, stream>>>(recD, recS, baseD, baseS, inv_in, inv_out);
        wprep_kernel<<<12,   256, 0, stream>>>(Wz, Wh, WzT, WhT);
        p4_gather  <<<2*NB,  256, 0, stream>>>(recD, recS, baseD, baseS, x, inv_out, inv_in, To, Ti);
        node_kernel<<<(N_NODES + 255) / 256, 256, 0, stream>>>(x, To, Ti, WzT, WhT, bz, bh,
                                                               linW, linb, (float*)d_out);
    } else {
        // compact fallback: To,Ti,inv_out,inv_in,WzT,WhT at front of ws
        float* fTo  = ws;
        float* fTi  = ws + 16 * N_NODES;
        float* fIo  = ws + 32 * N_NODES;
        float* fIi  = ws + 33 * N_NODES;
        float* fWzT = ws + 34 * N_NODES;
        float* fWhT = fWzT + CIN3 * HID;
        zero_kernel<<<2048, 256, 0, stream>>>(fTo, 34 * N_NODES);
        degree_compact<<<(N_EDGES + 255) / 256, 256, 0, stream>>>(ei, ew, fIo, fIi);
        rcp_compact<<<(N_NODES + 255) / 256, 256, 0, stream>>>(fIo, fIi);
        scatter_kernel<<<(N_EDGES * NF + 255) / 256, 256, 0, stream>>>(ei, x, fIo, fIi, fTo, fTi);
        wprep_kernel<<<12, 256, 0, stream>>>(Wz, Wh, fWzT, fWhT);
        node_kernel<<<(N_NODES + 255) / 256, 256, 0, stream>>>(x, fTo, fTi, fWzT, fWhT, bz, bh,
                                                               linW, linb, (float*)d_out);
    }
}